// Round 5
// baseline (248.909 us; speedup 1.0000x reference)
//
#include <hip/hip_runtime.h>
#include <stdint.h>

typedef float f32x4 __attribute__((ext_vector_type(4)));
typedef int   i32x8 __attribute__((ext_vector_type(8)));
typedef long  i64x2 __attribute__((ext_vector_type(2)));
typedef long  i64x4 __attribute__((ext_vector_type(4)));

#define VOCAB 4096
#define DIM   256
#define NROWS 65536            // 32*2048
#define SPLITS 4
#define COLS_PER (VOCAB/SPLITS) // 1024
#define CTILE 32
#define NT (COLS_PER/CTILE)     // 32 tiles
#define RPB 128                 // rows per block (2 waves x 64)
#define RGROUPS (NROWS/RPB)     // 512
#define SSCALE 4096.0f

#define GLOBAL_AS __attribute__((address_space(1)))
#define LDS_AS    __attribute__((address_space(3)))

#if defined(__has_builtin)
#if __has_builtin(__builtin_amdgcn_mfma_scale_f32_16x16x128_f8f6f4)
#define HAVE_MXFMA 1
#endif
#endif

// Pack 8 consecutive-k floats -> 8 fp8 bytes. A and B both use THIS helper,
// so any byte-permutation cancels in the MFMA contraction (A byte j always
// multiplies B byte j for the same k).
static __device__ __forceinline__ long pk8(float4 a, float4 b) {
    int lo = __builtin_amdgcn_cvt_pk_fp8_f32(a.x, a.y, 0, false);
    lo     = __builtin_amdgcn_cvt_pk_fp8_f32(a.z, a.w, lo, true);
    int hi = __builtin_amdgcn_cvt_pk_fp8_f32(b.x, b.y, 0, false);
    hi     = __builtin_amdgcn_cvt_pk_fp8_f32(b.z, b.w, hi, true);
    return (long)(unsigned)lo | ((long)hi << 32);
}
static __device__ __forceinline__ float4 sc4(float4 v, float s) {
    float4 r; r.x = s*v.x; r.y = s*v.y; r.z = s*v.z; r.w = s*v.w; return r;
}

// Prep: eimg = fp8(-2*S*emb) pre-swizzled so the DMA fill order IS the MFMA
// B-fragment order; e2s[v] = sum(emb[v]^2) (unscaled, used only for loss).
// Tile (32 cols, 8 KB): region r = sub*2+kb (2 KB) split in halves h (1 KB):
// byte [r*2048 + h*1024 + lane*16 + j]  <->  col = sub*16 + (lane&15),
// k-chunk = kb*128 + (lane>>4)*32 + h*16 + j.
__global__ void vq_prep(const float* __restrict__ emb, uint8_t* __restrict__ eimg,
                        float* __restrict__ e2s) {
    const int t = threadIdx.x, tile = blockIdx.x;
    const int C0 = tile * CTILE;
    const int l = t & 63, q = l >> 4, n = l & 15;
    const int r = t >> 6;               // sub*2 + kb
    const int sub = r >> 1, kb = r & 1;
    const float s = -2.0f * SSCALE;
    uint8_t* tb = eimg + (size_t)tile * 8192 + r * 2048 + l * 16;
    const float* erow = emb + (size_t)(C0 + sub*16 + n) * DIM + kb*128 + q*32;
    #pragma unroll
    for (int h = 0; h < 2; ++h) {
        const float4* p = (const float4*)(erow + h*16);
        i64x2 L;
        L.x = pk8(sc4(p[0], s), sc4(p[1], s));
        L.y = pk8(sc4(p[2], s), sc4(p[3], s));
        *(i64x2*)(tb + h*1024) = L;
    }
    // e2: 8 threads per col
    const int c = t >> 3, seg = t & 7;
    const float4* er = (const float4*)(emb + (size_t)(C0 + c) * DIM + seg*32);
    float ss = 0.f;
    #pragma unroll
    for (int i = 0; i < 8; ++i) {
        float4 v = er[i];
        ss += v.x*v.x + v.y*v.y + v.z*v.z + v.w*v.w;
    }
    ss += __shfl_xor(ss, 1); ss += __shfl_xor(ss, 2); ss += __shfl_xor(ss, 4);
    if (seg == 0) e2s[C0 + c] = ss;
}

// K1: MX-scaled fp8 argmin over -2*x.e (e2 dropped from selection: its spread
// is below the fp8 noise floor; exact e2 re-added for the loss in K2).
// Also emits per-rowgroup sum(||x||^2) from split-0 blocks (x already loaded).
__global__ __launch_bounds__(128, 3) void vq_argmin(
        const float* __restrict__ x, const uint8_t* __restrict__ eimg,
        float* __restrict__ cand, float* __restrict__ px2) {
    __shared__ __align__(16) uint8_t Bb[2][8192];
    __shared__ float x2s[2];

    const int tid  = threadIdx.x;
    const int wave = tid >> 6;
    const int lane = tid & 63;
    const int quad = lane >> 4;
    const int l16  = lane & 15;
    // split-outer: a rowgroup's 4 split-blocks are 512 apart -> same XCD (512%8==0)
    const int split    = blockIdx.x >> 9;
    const int rowgroup = blockIdx.x & (RGROUPS - 1);
    const int rowblock = rowgroup * RPB;
    const int waverow  = rowblock + wave * 64;
    const int colbase0 = split * COLS_PER;

    // ---- A fragments: fp8(x), 64 rows/wave, 64 VGPRs, register-resident ----
    // lane (q, m=l16) holds k = kb*128 + q*32 + (0..31), bytes in k order.
    i64x4 A[4][2];
    float ss = 0.f;
    #pragma unroll
    for (int rs = 0; rs < 4; ++rs) {
        const float* xrow = x + (size_t)(waverow + rs*16 + l16) * DIM + quad*32;
        #pragma unroll
        for (int kb = 0; kb < 2; ++kb) {
            const float4* p = (const float4*)(xrow + kb*128);
            float4 v0=p[0],v1=p[1],v2=p[2],v3=p[3],v4=p[4],v5=p[5],v6=p[6],v7=p[7];
            if (split == 0) {
                ss += v0.x*v0.x+v0.y*v0.y+v0.z*v0.z+v0.w*v0.w
                    + v1.x*v1.x+v1.y*v1.y+v1.z*v1.z+v1.w*v1.w
                    + v2.x*v2.x+v2.y*v2.y+v2.z*v2.z+v2.w*v2.w
                    + v3.x*v3.x+v3.y*v3.y+v3.z*v3.z+v3.w*v3.w
                    + v4.x*v4.x+v4.y*v4.y+v4.z*v4.z+v4.w*v4.w
                    + v5.x*v5.x+v5.y*v5.y+v5.z*v5.z+v5.w*v5.w
                    + v6.x*v6.x+v6.y*v6.y+v6.z*v6.z+v6.w*v6.w
                    + v7.x*v7.x+v7.y*v7.y+v7.z*v7.z+v7.w*v7.w;
            }
            i64x4 a;
            a.x = pk8(v0, v1); a.y = pk8(v2, v3);
            a.z = pk8(v4, v5); a.w = pk8(v6, v7);
            A[rs][kb] = a;
        }
    }
    if (split == 0) {
        #pragma unroll
        for (int off = 32; off; off >>= 1) ss += __shfl_down(ss, off);
        if (lane == 0) x2s[wave] = ss;
    }
    __syncthreads();
    if (split == 0 && tid == 0) px2[rowgroup] = x2s[0] + x2s[1];

    float rmin[4][4];
    #pragma unroll
    for (int rs = 0; rs < 4; ++rs)
        #pragma unroll
        for (int r = 0; r < 4; ++r) rmin[rs][r] = 3.402823466e+38f;

    // ---- Async stage one 8 KB tile: 4 DMA instrs per wave ----
    auto stage = [&](int ct, int buf) {
        const uint8_t* src = eimg + (size_t)(colbase0/CTILE + ct) * 8192
                             + wave*4096 + lane*16;
        uint8_t* dst = &Bb[buf][wave * 4096];          // wave-uniform base
        #pragma unroll
        for (int i = 0; i < 4; ++i)
            __builtin_amdgcn_global_load_lds((const GLOBAL_AS void*)(src + i*1024),
                                             (LDS_AS void*)(dst + i*1024), 16, 0, 0);
    };

    stage(0, 0);
    for (int ct = 0; ct < NT; ++ct) {
        const int cur = ct & 1;
        __syncthreads();                  // drains DMA; Bb[cur] ready, Bb[cur^1] free
        if (ct + 1 < NT) stage(ct + 1, cur ^ 1);

        const int colbase = colbase0 + ct * CTILE;
        #pragma unroll
        for (int sub = 0; sub < 2; ++sub) {
            f32x4 acc[4];
            #pragma unroll
            for (int rs = 0; rs < 4; ++rs) acc[rs] = (f32x4){0.f, 0.f, 0.f, 0.f};
            #pragma unroll
            for (int kb = 0; kb < 2; ++kb) {
                const int rb = (sub*2 + kb) * 2048;
                i64x2 L0 = *(const i64x2*)&Bb[cur][rb + lane*16];
                i64x2 L1 = *(const i64x2*)&Bb[cur][rb + 1024 + lane*16];
#ifdef HAVE_MXFMA
                i64x4 Bv; Bv.x = L0.x; Bv.y = L0.y; Bv.z = L1.x; Bv.w = L1.y;
                i32x8 b8 = __builtin_bit_cast(i32x8, Bv);
                #pragma unroll
                for (int rs = 0; rs < 4; ++rs)
                    acc[rs] = __builtin_amdgcn_mfma_scale_f32_16x16x128_f8f6f4(
                        __builtin_bit_cast(i32x8, A[rs][kb]), b8, acc[rs],
                        0, 0,                 // cbsz=fp8(e4m3), blgp=fp8(e4m3)
                        0, 0x7F7F7F7F,        // scale_a: E8M0 127 = 1.0 (any byte)
                        0, 0x7F7F7F7F);       // scale_b
#else
                #pragma unroll
                for (int rs = 0; rs < 4; ++rs) {
                    acc[rs] = __builtin_amdgcn_mfma_f32_16x16x32_fp8_fp8(A[rs][kb].x, L0.x, acc[rs], 0, 0, 0);
                    acc[rs] = __builtin_amdgcn_mfma_f32_16x16x32_fp8_fp8(A[rs][kb].y, L0.y, acc[rs], 0, 0, 0);
                    acc[rs] = __builtin_amdgcn_mfma_f32_16x16x32_fp8_fp8(A[rs][kb].z, L1.x, acc[rs], 0, 0, 0);
                    acc[rs] = __builtin_amdgcn_mfma_f32_16x16x32_fp8_fp8(A[rs][kb].w, L1.y, acc[rs], 0, 0, 0);
                }
#endif
            }
            const unsigned colv = (unsigned)(colbase + sub*16 + l16);
            // C layout: row = quad*4 + r, col = l16. Pack idx (12 bits == VOCAB)
            // into low mantissa -> one v_min_f32 carries (score, idx).
            #pragma unroll
            for (int rs = 0; rs < 4; ++rs)
                #pragma unroll
                for (int r = 0; r < 4; ++r) {
                    unsigned pk = (__float_as_uint(acc[rs][r]) & 0xFFFFF000u) | colv;
                    rmin[rs][r] = fminf(rmin[rs][r], __uint_as_float(pk));
                }
        }
    }

    // ---- Reduce across the 16 lanes of each quad, emit packed winner ----
    #pragma unroll
    for (int rs = 0; rs < 4; ++rs) {
        #pragma unroll
        for (int r = 0; r < 4; ++r) {
            float v = rmin[rs][r];
            v = fminf(v, __shfl_xor(v, 8));
            v = fminf(v, __shfl_xor(v, 4));
            v = fminf(v, __shfl_xor(v, 2));
            v = fminf(v, __shfl_xor(v, 1));
            if (l16 == 0)
                cand[(size_t)split * NROWS + waverow + rs*16 + quad*4 + r] = v;
        }
    }
}

// K2: merge splits, gather emb[idx] -> out (no x read), per-block loss partial
// sum of (score/S + e2[idx]) = (-2 x.e + e2) per row.
__global__ __launch_bounds__(256) void vq_out(
        const float* __restrict__ emb, const float* __restrict__ e2s,
        const float* __restrict__ cand, float* __restrict__ out,
        float* __restrict__ partial) {
    __shared__ int idx_lds[RPB];
    __shared__ float ssum[2];
    const int tid = threadIdx.x;
    const int rowblock = blockIdx.x * RPB;
    if (tid < RPB) {
        float m = cand[rowblock + tid];
        m = fminf(m, cand[1*NROWS + rowblock + tid]);
        m = fminf(m, cand[2*NROWS + rowblock + tid]);
        m = fminf(m, cand[3*NROWS + rowblock + tid]);
        unsigned u = __float_as_uint(m);
        int idx = (int)(u & 0xFFFu);
        idx_lds[tid] = idx;
        float srow = __uint_as_float(u & 0xFFFFF000u) * (1.0f / SSCALE) + e2s[idx];
        #pragma unroll
        for (int off = 32; off; off >>= 1) srow += __shfl_down(srow, off);
        if ((tid & 63) == 0) ssum[tid >> 6] = srow;
    }
    __syncthreads();
    if (tid == 0) partial[blockIdx.x] = ssum[0] + ssum[1];

    #pragma unroll 4
    for (int it = 0; it < 32; ++it) {
        int fi  = it * 256 + tid;          // 8192 float4 per 128-row tile
        int row = fi >> 6;
        int c4  = fi & 63;
        float4 q = ((const float4*)(emb + (size_t)idx_lds[row] * DIM))[c4];
        ((float4*)(out + (size_t)(rowblock + row) * DIM))[c4] = q;
    }
}

// K3: loss = 1.25/Nel * (sum px2 + sum partial)
__global__ void vq_loss(const float* __restrict__ px2, const float* __restrict__ p2,
                        float* __restrict__ loss_slot) {
    __shared__ float wsum[4];
    const int tid = threadIdx.x;
    float s = px2[tid] + px2[256 + tid] + p2[tid] + p2[256 + tid];
    #pragma unroll
    for (int off = 32; off; off >>= 1) s += __shfl_down(s, off);
    if ((tid & 63) == 0) wsum[tid >> 6] = s;
    __syncthreads();
    if (tid == 0)
        loss_slot[0] = (wsum[0] + wsum[1] + wsum[2] + wsum[3]) * (1.25f / 16777216.f);
}

extern "C" void kernel_launch(void* const* d_in, const int* in_sizes, int n_in,
                              void* d_out, int out_size, void* d_ws, size_t ws_size,
                              hipStream_t stream) {
    const float* x   = (const float*)d_in[0];   // [32,2048,256]
    const float* emb = (const float*)d_in[1];   // [4096,256]
    float* out = (float*)d_out;                 // 16777216 quantised_st + 1 loss

    uint8_t* eimg = (uint8_t*)d_ws;                                    // 1 MB
    float* e2s    = (float*)((char*)d_ws + (size_t)VOCAB*DIM);         // 16 KB
    float* cand   = (float*)((char*)e2s + VOCAB*4);                    // 1 MB
    float* px2    = (float*)((char*)cand + (size_t)SPLITS*NROWS*4);    // 2 KB
    float* p2     = (float*)((char*)px2 + RGROUPS*4);                  // 2 KB
    float* loss_slot = out + (size_t)NROWS * DIM;

    vq_prep<<<VOCAB/CTILE, 256, 0, stream>>>(emb, eimg, e2s);
    vq_argmin<<<RGROUPS*SPLITS, 128, 0, stream>>>(x, eimg, cand, px2);
    vq_out<<<RGROUPS, 256, 0, stream>>>(emb, e2s, cand, out, p2);
    vq_loss<<<1, 256, 0, stream>>>(px2, p2, loss_slot);
}

// Round 6
// 224.201 us; speedup vs baseline: 1.1102x; 1.1102x over previous
//
#include <hip/hip_runtime.h>
#include <stdint.h>

typedef float f32x4 __attribute__((ext_vector_type(4)));
typedef int   i32x8 __attribute__((ext_vector_type(8)));
typedef long  i64x2 __attribute__((ext_vector_type(2)));
typedef long  i64x4 __attribute__((ext_vector_type(4)));

#define VOCAB 4096
#define DIM   256
#define NROWS 65536             // 32*2048
#define SPLITS 4
#define COLS_PER (VOCAB/SPLITS) // 1024
#define CTILE 32
#define NT (COLS_PER/CTILE)     // 32 tiles
#define RPW 32                  // rows per (single-wave) block
#define WGRPS (NROWS/RPW)       // 2048 row-waves
#define SSCALE 4096.0f

#if defined(__has_builtin)
#if __has_builtin(__builtin_amdgcn_mfma_scale_f32_16x16x128_f8f6f4)
#define HAVE_MXFMA 1
#endif
#endif

// Pack 8 consecutive-k floats -> 8 fp8 bytes. A and B both use THIS helper,
// so any byte-permutation cancels in the MFMA contraction.
static __device__ __forceinline__ long pk8(float4 a, float4 b) {
    int lo = __builtin_amdgcn_cvt_pk_fp8_f32(a.x, a.y, 0, false);
    lo     = __builtin_amdgcn_cvt_pk_fp8_f32(a.z, a.w, lo, true);
    int hi = __builtin_amdgcn_cvt_pk_fp8_f32(b.x, b.y, 0, false);
    hi     = __builtin_amdgcn_cvt_pk_fp8_f32(b.z, b.w, hi, true);
    return (long)(unsigned)lo | ((long)hi << 32);
}
static __device__ __forceinline__ float4 sc4(float4 v, float s) {
    float4 r; r.x = s*v.x; r.y = s*v.y; r.z = s*v.z; r.w = s*v.w; return r;
}

// Prep: eimg = fp8(-2*S*emb) in per-lane fragment order (identical layout to R5):
// tile ct (32 cols, 8 KB): region r = sub*2+kb (2 KB), halves h (1 KB):
// byte [r*2048 + h*1024 + lane*16 + j] <-> col = sub*16 + (lane&15),
// k = kb*128 + (lane>>4)*32 + h*16 + j.   e2s[v] = sum(emb[v]^2) (loss only).
__global__ void vq_prep(const float* __restrict__ emb, uint8_t* __restrict__ eimg,
                        float* __restrict__ e2s) {
    const int t = threadIdx.x, tile = blockIdx.x;
    const int C0 = tile * CTILE;
    const int l = t & 63, q = l >> 4, n = l & 15;
    const int r = t >> 6;               // sub*2 + kb
    const int sub = r >> 1, kb = r & 1;
    const float s = -2.0f * SSCALE;
    uint8_t* tb = eimg + (size_t)tile * 8192 + r * 2048 + l * 16;
    const float* erow = emb + (size_t)(C0 + sub*16 + n) * DIM + kb*128 + q*32;
    #pragma unroll
    for (int h = 0; h < 2; ++h) {
        const float4* p = (const float4*)(erow + h*16);
        i64x2 L;
        L.x = pk8(sc4(p[0], s), sc4(p[1], s));
        L.y = pk8(sc4(p[2], s), sc4(p[3], s));
        *(i64x2*)(tb + h*1024) = L;
    }
    const int c = t >> 3, seg = t & 7;
    const float4* er = (const float4*)(emb + (size_t)(C0 + c) * DIM + seg*32);
    float ss = 0.f;
    #pragma unroll
    for (int i = 0; i < 8; ++i) {
        float4 v = er[i];
        ss += v.x*v.x + v.y*v.y + v.z*v.z + v.w*v.w;
    }
    ss += __shfl_xor(ss, 1); ss += __shfl_xor(ss, 2); ss += __shfl_xor(ss, 4);
    if (seg == 0) e2s[C0 + c] = ss;
}

// K1: single-wave blocks, NO LDS, NO barriers. Each wave: 32 register-resident
// x rows, streams B fragments global->VGPR from the L2-resident eimg.
__global__ __launch_bounds__(64, 4) void vq_argmin(
        const float* __restrict__ x, const uint8_t* __restrict__ eimg,
        float* __restrict__ cand, float* __restrict__ px2) {
    const int lane = threadIdx.x;
    const int quad = lane >> 4;
    const int l16  = lane & 15;
    const int split = blockIdx.x & (SPLITS - 1);   // inner: co-dispatched splits share x in L2
    const int wgrp  = blockIdx.x >> 2;             // 0..2047
    const int waverow  = wgrp * RPW;
    const int colbase0 = split * COLS_PER;

    // ---- A fragments: fp8(x), 32 rows/wave = 32 VGPRs ----
    i64x4 A[2][2];
    float ss = 0.f;
    #pragma unroll
    for (int rs = 0; rs < 2; ++rs) {
        const float* xrow = x + (size_t)(waverow + rs*16 + l16) * DIM + quad*32;
        #pragma unroll
        for (int kb = 0; kb < 2; ++kb) {
            const float4* p = (const float4*)(xrow + kb*128);
            float4 v0=p[0],v1=p[1],v2=p[2],v3=p[3],v4=p[4],v5=p[5],v6=p[6],v7=p[7];
            if (split == 0) {
                ss += v0.x*v0.x+v0.y*v0.y+v0.z*v0.z+v0.w*v0.w
                    + v1.x*v1.x+v1.y*v1.y+v1.z*v1.z+v1.w*v1.w
                    + v2.x*v2.x+v2.y*v2.y+v2.z*v2.z+v2.w*v2.w
                    + v3.x*v3.x+v3.y*v3.y+v3.z*v3.z+v3.w*v3.w
                    + v4.x*v4.x+v4.y*v4.y+v4.z*v4.z+v4.w*v4.w
                    + v5.x*v5.x+v5.y*v5.y+v5.z*v5.z+v5.w*v5.w
                    + v6.x*v6.x+v6.y*v6.y+v6.z*v6.z+v6.w*v6.w
                    + v7.x*v7.x+v7.y*v7.y+v7.z*v7.z+v7.w*v7.w;
            }
            i64x4 a;
            a.x = pk8(v0, v1); a.y = pk8(v2, v3);
            a.z = pk8(v4, v5); a.w = pk8(v6, v7);
            A[rs][kb] = a;
        }
    }
    if (split == 0) {
        #pragma unroll
        for (int off = 32; off; off >>= 1) ss += __shfl_down(ss, off);
        if (lane == 0) px2[wgrp] = ss;
    }

    float rmin[2][4];
    #pragma unroll
    for (int rs = 0; rs < 2; ++rs)
        #pragma unroll
        for (int r = 0; r < 4; ++r) rmin[rs][r] = 3.402823466e+38f;

    const uint8_t* tb0 = eimg + ((size_t)(colbase0 / CTILE) << 13) + (lane << 4);

    #pragma unroll 2
    for (int ct = 0; ct < NT; ++ct) {
        const uint8_t* tb = tb0 + ((size_t)ct << 13);
        // B fragments direct to VGPR: 8 x dwordx4 (i32x8 halves at +0/+1024).
        union BU { i32x8 v; i64x4 q; struct { int4 lo, hi; } s; } b[2][2];
        #pragma unroll
        for (int sub = 0; sub < 2; ++sub)
            #pragma unroll
            for (int kb = 0; kb < 2; ++kb) {
                const uint8_t* pB = tb + (sub*2 + kb) * 2048;
                b[sub][kb].s.lo = *(const int4*)pB;
                b[sub][kb].s.hi = *(const int4*)(pB + 1024);
            }
        const int colbase = colbase0 + ct * CTILE;
        #pragma unroll
        for (int sub = 0; sub < 2; ++sub) {
            f32x4 acc[2];
            acc[0] = (f32x4){0.f,0.f,0.f,0.f};
            acc[1] = (f32x4){0.f,0.f,0.f,0.f};
            #pragma unroll
            for (int kb = 0; kb < 2; ++kb) {
#ifdef HAVE_MXFMA
                #pragma unroll
                for (int rs = 0; rs < 2; ++rs)
                    acc[rs] = __builtin_amdgcn_mfma_scale_f32_16x16x128_f8f6f4(
                        __builtin_bit_cast(i32x8, A[rs][kb]), b[sub][kb].v, acc[rs],
                        0, 0, 0, 0x7F7F7F7F, 0, 0x7F7F7F7F);
#else
                #pragma unroll
                for (int rs = 0; rs < 2; ++rs) {
                    acc[rs] = __builtin_amdgcn_mfma_f32_16x16x32_fp8_fp8(A[rs][kb].x, b[sub][kb].q.x, acc[rs], 0, 0, 0);
                    acc[rs] = __builtin_amdgcn_mfma_f32_16x16x32_fp8_fp8(A[rs][kb].y, b[sub][kb].q.y, acc[rs], 0, 0, 0);
                    acc[rs] = __builtin_amdgcn_mfma_f32_16x16x32_fp8_fp8(A[rs][kb].z, b[sub][kb].q.z, acc[rs], 0, 0, 0);
                    acc[rs] = __builtin_amdgcn_mfma_f32_16x16x32_fp8_fp8(A[rs][kb].w, b[sub][kb].q.w, acc[rs], 0, 0, 0);
                }
#endif
            }
            const unsigned colv = (unsigned)(colbase + sub*16 + l16);
            // C layout: row = quad*4 + r, col = l16. idx packed in low 12 mantissa
            // bits -> one v_min_f32 carries (score, idx).
            #pragma unroll
            for (int rs = 0; rs < 2; ++rs)
                #pragma unroll
                for (int r = 0; r < 4; ++r) {
                    unsigned pk = (__float_as_uint(acc[rs][r]) & 0xFFFFF000u) | colv;
                    rmin[rs][r] = fminf(rmin[rs][r], __uint_as_float(pk));
                }
        }
    }

    // ---- Reduce across the 16 lanes of each quad, emit packed winner ----
    #pragma unroll
    for (int rs = 0; rs < 2; ++rs) {
        #pragma unroll
        for (int r = 0; r < 4; ++r) {
            float v = rmin[rs][r];
            v = fminf(v, __shfl_xor(v, 8));
            v = fminf(v, __shfl_xor(v, 4));
            v = fminf(v, __shfl_xor(v, 2));
            v = fminf(v, __shfl_xor(v, 1));
            if (l16 == 0)
                cand[(size_t)split * NROWS + waverow + rs*16 + quad*4 + r] = v;
        }
    }
}

// K2: merge splits, gather emb[idx] -> out (no x read), per-block loss partial
// of (score/S + e2[idx]) = (-2 x.e + e2) per row.  64 rows per block.
__global__ __launch_bounds__(256) void vq_out(
        const float* __restrict__ emb, const float* __restrict__ e2s,
        const float* __restrict__ cand, float* __restrict__ out,
        float* __restrict__ partial) {
    __shared__ int idx_lds[64];
    const int tid = threadIdx.x;
    const int rowblock = blockIdx.x * 64;
    if (tid < 64) {
        float m = cand[rowblock + tid];
        m = fminf(m, cand[1*NROWS + rowblock + tid]);
        m = fminf(m, cand[2*NROWS + rowblock + tid]);
        m = fminf(m, cand[3*NROWS + rowblock + tid]);
        unsigned u = __float_as_uint(m);
        int idx = (int)(u & 0xFFFu);
        idx_lds[tid] = idx;
        float srow = __uint_as_float(u & 0xFFFFF000u) * (1.0f / SSCALE) + e2s[idx];
        #pragma unroll
        for (int off = 32; off; off >>= 1) srow += __shfl_down(srow, off);
        if (tid == 0) partial[blockIdx.x] = srow;
    }
    __syncthreads();

    #pragma unroll 4
    for (int it = 0; it < 16; ++it) {
        int fi  = it * 256 + tid;          // 4096 float4 per 64-row tile
        int row = fi >> 6;
        int c4  = fi & 63;
        float4 q = ((const float4*)(emb + (size_t)idx_lds[row] * DIM))[c4];
        ((float4*)(out + (size_t)(rowblock + row) * DIM))[c4] = q;
    }
}

// K3: loss = 1.25/Nel * (sum px2[2048] + sum partial[1024])
__global__ void vq_loss(const float* __restrict__ px2, const float* __restrict__ p2,
                        float* __restrict__ loss_slot) {
    __shared__ float wsum[4];
    const int tid = threadIdx.x;
    float s = 0.f;
    #pragma unroll
    for (int i = 0; i < 8; ++i) s += px2[i * 256 + tid];
    #pragma unroll
    for (int i = 0; i < 4; ++i) s += p2[i * 256 + tid];
    #pragma unroll
    for (int off = 32; off; off >>= 1) s += __shfl_down(s, off);
    if ((tid & 63) == 0) wsum[tid >> 6] = s;
    __syncthreads();
    if (tid == 0)
        loss_slot[0] = (wsum[0] + wsum[1] + wsum[2] + wsum[3]) * (1.25f / 16777216.f);
}

extern "C" void kernel_launch(void* const* d_in, const int* in_sizes, int n_in,
                              void* d_out, int out_size, void* d_ws, size_t ws_size,
                              hipStream_t stream) {
    const float* x   = (const float*)d_in[0];   // [32,2048,256]
    const float* emb = (const float*)d_in[1];   // [4096,256]
    float* out = (float*)d_out;                 // 16777216 quantised_st + 1 loss

    uint8_t* eimg = (uint8_t*)d_ws;                                    // 1 MB
    float* e2s    = (float*)((char*)d_ws + (size_t)VOCAB*DIM);         // 16 KB
    float* cand   = (float*)((char*)e2s + VOCAB*4);                    // 1 MB
    float* px2    = (float*)((char*)cand + (size_t)SPLITS*NROWS*4);    // 8 KB
    float* p2     = (float*)((char*)px2 + WGRPS*4);                    // 4 KB
    float* loss_slot = out + (size_t)NROWS * DIM;

    vq_prep<<<VOCAB/CTILE, 256, 0, stream>>>(emb, eimg, e2s);
    vq_argmin<<<WGRPS*SPLITS, 64, 0, stream>>>(x, eimg, cand, px2);
    vq_out<<<NROWS/64, 256, 0, stream>>>(emb, e2s, cand, out, p2);
    vq_loss<<<1, 256, 0, stream>>>(px2, p2, loss_slot);
}